// Round 1
// baseline (381.156 us; speedup 1.0000x reference)
//
#include <hip/hip_runtime.h>

#define NB 8
#define NS 4096
#define ND 1024
#define NH 16
#define NF 4096

typedef __attribute__((ext_vector_type(8))) short s16x8;
typedef __attribute__((ext_vector_type(4))) float f32x4;

__device__ __forceinline__ unsigned short f2bf(float x) {
    unsigned u = __float_as_uint(x);
    u += 0x7fffu + ((u >> 16) & 1u);
    return (unsigned short)(u >> 16);
}

// -------- generic partial matvec: Pout[kp][b][c] = sum_{k in chunk} xt(b,k) * W[k][c]
// xt(b,k) = per_head ? xd[b*16 + (c>>6)][k]
//         : nprev==0 ? xd[b][k]
//         : relu?(sum_p Pin[p][b][k] + bias_in[k])
__global__ void __launch_bounds__(256) mv_k(const float* __restrict__ xd,
        const float* __restrict__ Pin, int nprev,
        const float* __restrict__ bias_in, int relu_in, int per_head,
        const float* __restrict__ W, int K, int Cout, int kchunk,
        float* __restrict__ Pout)
{
    int b = blockIdx.x, cblk = blockIdx.y, kp = blockIdx.z;
    int c = cblk * 256 + threadIdx.x;
    int k0 = kp * kchunk;
    float acc = 0.f;
    if (per_head) {
        const float* xr = xd + ((size_t)(b * NH + (c >> 6))) * 1024;
        #pragma unroll 4
        for (int k = k0; k < k0 + kchunk; ++k)
            acc += xr[k] * W[(size_t)k * Cout + c];
    } else {
        __shared__ float xs[1024];
        for (int k = threadIdx.x; k < kchunk; k += 256) {
            int kk = k0 + k;
            float t;
            if (nprev == 0) {
                t = xd[(size_t)b * K + kk];
            } else {
                t = bias_in[kk];
                for (int p = 0; p < nprev; ++p)
                    t += Pin[((size_t)(p * NB + b)) * K + kk];
                if (relu_in) t = fmaxf(t, 0.f);
            }
            xs[k] = t;
        }
        __syncthreads();
        #pragma unroll 4
        for (int k = 0; k < kchunk; ++k)
            acc += xs[k] * W[(size_t)(k0 + k) * Cout + c];
    }
    Pout[((size_t)(kp * NB + b)) * Cout + c] = acc;
}

// -------- u[b,h,d] = sum_{j<64} Wk[d][h*64+j] * Q2[b][h*64+j], stored bf16
__global__ void __launch_bounds__(256) u_k(const float* __restrict__ Q2p,
        const float* __restrict__ bq, const float* __restrict__ Wk,
        unsigned short* __restrict__ u16)
{
    int bh = blockIdx.x;               // b*16+h
    int b = bh >> 4, h = bh & 15;
    int lane = threadIdx.x & 63, wv = threadIdx.x >> 6;
    int cc = h * 64 + lane;
    float q = bq[cc];
    for (int p = 0; p < 4; ++p) q += Q2p[((size_t)(p * NB + b)) * 1024 + cc];
    int dbase = blockIdx.y * 256;
    #pragma unroll 4
    for (int d = dbase + wv; d < dbase + 256; d += 4) {
        float v = Wk[(size_t)d * 1024 + cc] * q;
        for (int off = 32; off; off >>= 1) v += __shfl_down(v, off);
        if (lane == 0) u16[(size_t)bh * 1024 + d] = f2bf(v);
    }
}

// -------- scores[b][h][s] = (key[b,s,:] . u[b,h,:]) / 32 via MFMA 16x16x32 bf16
__global__ void __launch_bounds__(256) scores_k(const float* __restrict__ key,
        const unsigned short* __restrict__ u16, float* __restrict__ sc)
{
    __shared__ __align__(16) unsigned short ul[16][1032];
    int b = blockIdx.x;
    int tid = threadIdx.x;
    // stage u16[b] (16x1024 bf16 = 32KB) into LDS
    const uint4* src = (const uint4*)(u16 + (size_t)b * NH * 1024);
    for (int v = tid; v < 2048; v += 256) {
        int h = v >> 7;
        int col = (v & 127) * 8;
        *(uint4*)&ul[h][col] = src[v];
    }
    __syncthreads();
    int lane = tid & 63, wv = tid >> 6;
    int r = lane & 15, g = lane >> 4;
    int s0 = blockIdx.y * 128 + wv * 32;   // this wave: tiles s0 and s0+16
    const float* kp0 = key + ((size_t)(b * NS + s0 + r)) * ND + g * 8;
    f32x4 acc0 = {0.f, 0.f, 0.f, 0.f}, acc1 = {0.f, 0.f, 0.f, 0.f};
    for (int k = 0; k < 1024; k += 32) {
        s16x8 af = *(const s16x8*)&ul[r][k + g * 8];
        const float* p0 = kp0 + k;
        float4 x0 = *(const float4*)p0;
        float4 x1 = *(const float4*)(p0 + 4);
        s16x8 bf0;
        bf0[0]=(short)f2bf(x0.x); bf0[1]=(short)f2bf(x0.y);
        bf0[2]=(short)f2bf(x0.z); bf0[3]=(short)f2bf(x0.w);
        bf0[4]=(short)f2bf(x1.x); bf0[5]=(short)f2bf(x1.y);
        bf0[6]=(short)f2bf(x1.z); bf0[7]=(short)f2bf(x1.w);
        acc0 = __builtin_amdgcn_mfma_f32_16x16x32_bf16(af, bf0, acc0, 0, 0, 0);
        const float* p1 = p0 + 16 * ND;
        float4 y0 = *(const float4*)p1;
        float4 y1 = *(const float4*)(p1 + 4);
        s16x8 bf1;
        bf1[0]=(short)f2bf(y0.x); bf1[1]=(short)f2bf(y0.y);
        bf1[2]=(short)f2bf(y0.z); bf1[3]=(short)f2bf(y0.w);
        bf1[4]=(short)f2bf(y1.x); bf1[5]=(short)f2bf(y1.y);
        bf1[6]=(short)f2bf(y1.z); bf1[7]=(short)f2bf(y1.w);
        acc1 = __builtin_amdgcn_mfma_f32_16x16x32_bf16(af, bf1, acc1, 0, 0, 0);
    }
    const float scl = 1.f / 32.f;   // 1/sqrt(1024)
    #pragma unroll
    for (int j = 0; j < 4; ++j) {
        int h = g * 4 + j;
        sc[((size_t)(b * NH + h)) * NS + s0 + r]      = acc0[j] * scl;
        sc[((size_t)(b * NH + h)) * NS + s0 + 16 + r] = acc1[j] * scl;
    }
}

// -------- softmax over s for each (b,h); writes w transposed [b][s][h]
__global__ void __launch_bounds__(256) softmax_k(const float* __restrict__ sc,
        float* __restrict__ w)
{
    int bh = blockIdx.x;
    int b = bh >> 4, h = bh & 15;
    const float* row = sc + (size_t)bh * NS;
    __shared__ float sd[4];
    int tid = threadIdx.x;
    float mx = -3.4e38f;
    for (int s = tid; s < NS; s += 256) mx = fmaxf(mx, row[s]);
    for (int off = 32; off; off >>= 1) mx = fmaxf(mx, __shfl_down(mx, off));
    if ((tid & 63) == 0) sd[tid >> 6] = mx;
    __syncthreads();
    mx = fmaxf(fmaxf(sd[0], sd[1]), fmaxf(sd[2], sd[3]));
    __syncthreads();
    float sum = 0.f;
    for (int s = tid; s < NS; s += 256) sum += __expf(row[s] - mx);
    for (int off = 32; off; off >>= 1) sum += __shfl_down(sum, off);
    if ((tid & 63) == 0) sd[tid >> 6] = sum;
    __syncthreads();
    float total = sd[0] + sd[1] + sd[2] + sd[3];
    float inv = 1.f / total;
    for (int s = tid; s < NS; s += 256)
        w[((size_t)(b * NS + s)) * NH + h] = __expf(row[s] - mx) * inv;
}

// -------- pooled partial: pp[sc][b][h][d] = sum_{s in chunk} w[b][s][h]*value[b][s][d]
__global__ void __launch_bounds__(256) pool_k(const float* __restrict__ value,
        const float* __restrict__ w, float* __restrict__ pp)
{
    int b = blockIdx.x;
    int d = blockIdx.y * 256 + threadIdx.x;
    int s0 = blockIdx.z * 256;
    const float* vp = value + ((size_t)(b * NS + s0)) * ND + d;
    const float4* wp = (const float4*)(w + ((size_t)(b * NS + s0)) * NH);
    float4 a0 = {0,0,0,0}, a1 = {0,0,0,0}, a2 = {0,0,0,0}, a3 = {0,0,0,0};
    for (int s = 0; s < 256; ++s) {
        float v = vp[(size_t)s * ND];
        float4 w0 = wp[s * 4 + 0], w1 = wp[s * 4 + 1];
        float4 w2 = wp[s * 4 + 2], w3 = wp[s * 4 + 3];
        a0.x += w0.x * v; a0.y += w0.y * v; a0.z += w0.z * v; a0.w += w0.w * v;
        a1.x += w1.x * v; a1.y += w1.y * v; a1.z += w1.z * v; a1.w += w1.w * v;
        a2.x += w2.x * v; a2.y += w2.y * v; a2.z += w2.z * v; a2.w += w2.w * v;
        a3.x += w3.x * v; a3.y += w3.y * v; a3.z += w3.z * v; a3.w += w3.w * v;
    }
    float* o = pp + ((size_t)((blockIdx.z * NB + b) * NH)) * 1024 + d;
    o[0*1024]=a0.x;  o[1*1024]=a0.y;  o[2*1024]=a0.z;  o[3*1024]=a0.w;
    o[4*1024]=a1.x;  o[5*1024]=a1.y;  o[6*1024]=a1.z;  o[7*1024]=a1.w;
    o[8*1024]=a2.x;  o[9*1024]=a2.y;  o[10*1024]=a2.z; o[11*1024]=a2.w;
    o[12*1024]=a3.x; o[13*1024]=a3.y; o[14*1024]=a3.z; o[15*1024]=a3.w;
}

// -------- m[b][h][d] = sum over 16 s-chunks
__global__ void __launch_bounds__(256) poolred_k(const float* __restrict__ pp,
        float* __restrict__ m)
{
    int i = blockIdx.x * 256 + threadIdx.x;   // 131072 total
    float s = 0.f;
    #pragma unroll
    for (int c = 0; c < 16; ++c) s += pp[(size_t)c * 131072 + i];
    m[i] = s;
}

// -------- layernorm: t = sum_p P[p][b][c] + bias[c] + add[b][c]; out = LN(t)*g+be
__global__ void __launch_bounds__(256) ln_k(const float* __restrict__ P,
        const float* __restrict__ bias, const float* __restrict__ add,
        const float* __restrict__ g, const float* __restrict__ be,
        float* __restrict__ out)
{
    int b = blockIdx.x, tid = threadIdx.x;
    __shared__ float buf[1024];
    __shared__ float sd[4];
    float loc = 0.f;
    for (int i = 0; i < 4; ++i) {
        int c = i * 256 + tid;
        float t = bias[c] + add[(size_t)b * 1024 + c];
        for (int p = 0; p < 4; ++p) t += P[((size_t)(p * NB + b)) * 1024 + c];
        buf[c] = t; loc += t;
    }
    for (int off = 32; off; off >>= 1) loc += __shfl_down(loc, off);
    if ((tid & 63) == 0) sd[tid >> 6] = loc;
    __syncthreads();
    float mu = (sd[0] + sd[1] + sd[2] + sd[3]) * (1.f / 1024.f);
    __syncthreads();
    float v = 0.f;
    for (int i = 0; i < 4; ++i) { float t = buf[i * 256 + tid] - mu; v += t * t; }
    for (int off = 32; off; off >>= 1) v += __shfl_down(v, off);
    if ((tid & 63) == 0) sd[tid >> 6] = v;
    __syncthreads();
    float var = (sd[0] + sd[1] + sd[2] + sd[3]) * (1.f / 1024.f);
    float rs = rsqrtf(var + 1e-6f);
    for (int i = 0; i < 4; ++i) {
        int c = i * 256 + tid;
        out[(size_t)b * 1024 + c] = (buf[c] - mu) * rs * g[c] + be[c];
    }
}

extern "C" void kernel_launch(void* const* d_in, const int* in_sizes, int n_in,
                              void* d_out, int out_size, void* d_ws, size_t ws_size,
                              hipStream_t stream)
{
    const float* key   = (const float*)d_in[0];
    const float* value = (const float*)d_in[1];
    const float* dec   = (const float*)d_in[2];
    const float* Wq = (const float*)d_in[3];  const float* bq = (const float*)d_in[4];
    const float* Wk = (const float*)d_in[5];  /* bk cancels in softmax */
    const float* Wv = (const float*)d_in[7];  const float* bv = (const float*)d_in[8];
    const float* Wo = (const float*)d_in[9];  const float* bo = (const float*)d_in[10];
    const float* W1 = (const float*)d_in[11]; const float* b1 = (const float*)d_in[12];
    const float* W2 = (const float*)d_in[13]; const float* b2 = (const float*)d_in[14];
    const float* g2 = (const float*)d_in[15]; const float* be2 = (const float*)d_in[16];
    const float* gf = (const float*)d_in[17]; const float* bef = (const float*)d_in[18];

    float* ws = (float*)d_ws;
    float* V1p  = ws;                  // [4][8][1024]
    float* t1p  = V1p  + 32768;
    float* Q2p  = t1p  + 32768;
    float* avp  = Q2p  + 32768;
    float* t2p  = avp  + 32768;
    float* ff2p = t2p  + 32768;
    float* xbuf = ff2p + 32768;        // [8][1024]
    float* ff1p = xbuf + 8192;         // [4][8][4096]
    float* mb   = ff1p + 131072;       // [8][16][1024]
    float* scb  = mb   + 131072;       // [8][16][4096]
    float* wsh  = scb  + 524288;       // [8][4096][16]
    float* plp  = wsh  + 524288;       // [16][8][16][1024]
    unsigned short* u16 = (unsigned short*)(plp + 2097152);   // [8][16][1024] bf16

    dim3 blk(256);

    // prologue: V1 = dec@Wv ; t1 = (V1+bv)@Wo ; Q2 = (t1+bo)@Wq  (mha1 degenerates)
    mv_k<<<dim3(8,4,4), blk, 0, stream>>>(dec,  nullptr, 0, nullptr, 0, 0, Wv, 1024, 1024, 256, V1p);
    mv_k<<<dim3(8,4,4), blk, 0, stream>>>(nullptr, V1p, 4, bv, 0, 0, Wo, 1024, 1024, 256, t1p);
    mv_k<<<dim3(8,4,4), blk, 0, stream>>>(nullptr, t1p, 4, bo, 0, 0, Wq, 1024, 1024, 256, Q2p);

    // u[b,h,:] = Wk[:,head_h] @ Q2[b,head_h]  (bf16)
    u_k<<<dim3(128,4), blk, 0, stream>>>(Q2p, bq, Wk, u16);

    // scores over key, softmax, pool over value
    scores_k<<<dim3(8,32), blk, 0, stream>>>(key, u16, scb);
    softmax_k<<<dim3(128), blk, 0, stream>>>(scb, wsh);
    pool_k<<<dim3(8,4,16), blk, 0, stream>>>(value, wsh, plp);
    poolred_k<<<dim3(512), blk, 0, stream>>>(plp, mb);

    // av = m@Wv(per-head) ; t2 = (av+bv)@Wo ; x = LN(t2+bo+dec)
    mv_k<<<dim3(8,4,4), blk, 0, stream>>>(mb, nullptr, 0, nullptr, 0, 1, Wv, 1024, 1024, 256, avp);
    mv_k<<<dim3(8,4,4), blk, 0, stream>>>(nullptr, avp, 4, bv, 0, 0, Wo, 1024, 1024, 256, t2p);
    ln_k<<<dim3(8), blk, 0, stream>>>(t2p, bo, dec, g2, be2, xbuf);

    // ff: relu(x@W1+b1)@W2 + b2 + x, then final LN
    mv_k<<<dim3(8,16,4), blk, 0, stream>>>(xbuf, nullptr, 0, nullptr, 0, 0, W1, 1024, 4096, 256, ff1p);
    mv_k<<<dim3(8,4,4),  blk, 0, stream>>>(nullptr, ff1p, 4, b1, 1, 0, W2, 4096, 1024, 1024, ff2p);
    ln_k<<<dim3(8), blk, 0, stream>>>(ff2p, b2, xbuf, gf, bef, (float*)d_out);

    (void)in_sizes; (void)n_in; (void)out_size; (void)ws_size;
}

// Round 2
// 247.668 us; speedup vs baseline: 1.5390x; 1.5390x over previous
//
#include <hip/hip_runtime.h>

#define NB 8
#define NS 4096
#define ND 1024
#define NH 16
#define NF 4096

typedef __attribute__((ext_vector_type(8))) short s16x8;
typedef __attribute__((ext_vector_type(4))) float f32x4;

__device__ __forceinline__ unsigned short f2bf(float x) {
    unsigned u = __float_as_uint(x);
    u += 0x7fffu + ((u >> 16) & 1u);
    return (unsigned short)(u >> 16);
}

__device__ __forceinline__ s16x8 pack8(float4 a, float4 b) {
    s16x8 r;
    r[0]=(short)f2bf(a.x); r[1]=(short)f2bf(a.y); r[2]=(short)f2bf(a.z); r[3]=(short)f2bf(a.w);
    r[4]=(short)f2bf(b.x); r[5]=(short)f2bf(b.y); r[6]=(short)f2bf(b.z); r[7]=(short)f2bf(b.w);
    return r;
}

// -------- batched matvec partial: Pout[kp][b][c] = sum_{k in chunk} x[b][k]*W[k][c]
// All 8 b's per thread (8 acc), W read ONCE. x chunk staged in LDS [k][b].
// x[b][k]: per_head ? xd[(b*16 + c>>6)][k]
//        : nprev==0 ? xd[b*K+k] : act(sum_p Pin[(p*8+b)*K+k] + bias_in[k])
__global__ void __launch_bounds__(256) mv8_k(const float* __restrict__ xd,
        const float* __restrict__ Pin, int nprev, const float* __restrict__ bias_in,
        int relu_in, int per_head,
        const float* __restrict__ W, int K, int Cout, int KC,
        float* __restrict__ Pout)
{
    __shared__ float xs[1024];        // up to KC=128: [KC][8]
    int tid = threadIdx.x;
    int c = blockIdx.x * 256 + tid;
    int k0 = blockIdx.y * KC;
    int base = 0;
    if (per_head) {
        int wv = tid >> 6, lane = tid & 63;
        int h = (blockIdx.x * 256 + wv * 64) >> 6;     // uniform per wave
        base = wv * KC * 8;
        for (int i = lane; i < KC * 8; i += 64) {
            int k = i >> 3, b = i & 7;
            xs[base + i] = xd[((size_t)(b * NH + h)) * 1024 + k0 + k];
        }
    } else {
        for (int i = tid; i < KC * 8; i += 256) {
            int k = i >> 3, b = i & 7;
            int kk = k0 + k;
            float t;
            if (nprev == 0) {
                t = xd[(size_t)b * K + kk];
            } else {
                t = bias_in[kk];
                #pragma unroll 4
                for (int p = 0; p < nprev; ++p)
                    t += Pin[((size_t)(p * 8 + b)) * K + kk];
                if (relu_in) t = fmaxf(t, 0.f);
            }
            xs[i] = t;
        }
    }
    __syncthreads();
    const float* Wp = W + (size_t)k0 * Cout + c;
    float acc[8] = {0,0,0,0,0,0,0,0};
    #pragma unroll 4
    for (int k = 0; k < KC; ++k) {
        float wv = Wp[(size_t)k * Cout];
        float4 x0 = *(const float4*)&xs[base + k * 8];
        float4 x1 = *(const float4*)&xs[base + k * 8 + 4];
        acc[0] += x0.x * wv; acc[1] += x0.y * wv; acc[2] += x0.z * wv; acc[3] += x0.w * wv;
        acc[4] += x1.x * wv; acc[5] += x1.y * wv; acc[6] += x1.z * wv; acc[7] += x1.w * wv;
    }
    float* op = Pout + ((size_t)blockIdx.y * 8) * Cout + c;
    #pragma unroll
    for (int b = 0; b < 8; ++b) op[(size_t)b * Cout] = acc[b];
}

// -------- u[b,h,d] = sum_{j<64} Wk[d][h*64+j] * Q2[b][h*64+j], bf16 out
__global__ void __launch_bounds__(256) u_k(const float* __restrict__ Q2p,
        const float* __restrict__ bq, const float* __restrict__ Wk,
        unsigned short* __restrict__ u16)
{
    int bh = blockIdx.x;               // b*16+h
    int b = bh >> 4, h = bh & 15;
    int lane = threadIdx.x & 63, wv = threadIdx.x >> 6;
    int cc = h * 64 + lane;
    float q = bq[cc];
    #pragma unroll 8
    for (int p = 0; p < 32; ++p) q += Q2p[((size_t)(p * 8 + b)) * 1024 + cc];
    int dbase = blockIdx.y * 256;
    #pragma unroll 4
    for (int d = dbase + wv; d < dbase + 256; d += 4) {
        float v = Wk[(size_t)d * 1024 + cc] * q;
        for (int off = 32; off; off >>= 1) v += __shfl_down(v, off);
        if (lane == 0) u16[(size_t)bh * 1024 + d] = f2bf(v);
    }
}

// -------- scores[b][h][s] = (key[b,s,:] . u[b,h,:]) / 32 via MFMA, deep pipeline
__global__ void __launch_bounds__(256) scores_k(const float* __restrict__ key,
        const unsigned short* __restrict__ u16, float* __restrict__ sc)
{
    __shared__ __align__(16) unsigned short ul[16][1032];
    int b = blockIdx.x, tid = threadIdx.x;
    const uint4* src = (const uint4*)(u16 + (size_t)b * NH * 1024);
    for (int v = tid; v < 2048; v += 256) {
        int h = v >> 7, col = (v & 127) * 8;
        *(uint4*)&ul[h][col] = src[v];
    }
    __syncthreads();
    int lane = tid & 63, wv = tid >> 6;
    int r = lane & 15, g = lane >> 4;
    int s0 = blockIdx.y * 128 + wv * 32;
    const float* kp0 = key + ((size_t)(b * NS + s0 + r)) * ND + g * 8;
    const float* kp1 = kp0 + 16 * ND;
    f32x4 acc0 = {0.f,0.f,0.f,0.f}, acc1 = {0.f,0.f,0.f,0.f};
    float4 c[8], n[8];
    #pragma unroll
    for (int j = 0; j < 2; ++j) {
        c[j]     = *(const float4*)(kp0 + j * 4);
        c[2 + j] = *(const float4*)(kp1 + j * 4);
        c[4 + j] = *(const float4*)(kp0 + 32 + j * 4);
        c[6 + j] = *(const float4*)(kp1 + 32 + j * 4);
    }
    #pragma unroll
    for (int k = 0; k < 1024; k += 64) {
        int kn = k + 64;
        if (kn < 1024) {
            #pragma unroll
            for (int j = 0; j < 2; ++j) {
                n[j]     = *(const float4*)(kp0 + kn + j * 4);
                n[2 + j] = *(const float4*)(kp1 + kn + j * 4);
                n[4 + j] = *(const float4*)(kp0 + kn + 32 + j * 4);
                n[6 + j] = *(const float4*)(kp1 + kn + 32 + j * 4);
            }
        }
        s16x8 a0 = *(const s16x8*)&ul[r][k + g * 8];
        acc0 = __builtin_amdgcn_mfma_f32_16x16x32_bf16(a0, pack8(c[0], c[1]), acc0, 0, 0, 0);
        acc1 = __builtin_amdgcn_mfma_f32_16x16x32_bf16(a0, pack8(c[2], c[3]), acc1, 0, 0, 0);
        s16x8 a1 = *(const s16x8*)&ul[r][k + 32 + g * 8];
        acc0 = __builtin_amdgcn_mfma_f32_16x16x32_bf16(a1, pack8(c[4], c[5]), acc0, 0, 0, 0);
        acc1 = __builtin_amdgcn_mfma_f32_16x16x32_bf16(a1, pack8(c[6], c[7]), acc1, 0, 0, 0);
        #pragma unroll
        for (int j = 0; j < 8; ++j) c[j] = n[j];
    }
    const float scl = 1.f / 32.f;   // 1/sqrt(1024)
    #pragma unroll
    for (int j = 0; j < 4; ++j) {
        int h = g * 4 + j;
        sc[((size_t)(b * NH + h)) * NS + s0 + r]      = acc0[j] * scl;
        sc[((size_t)(b * NH + h)) * NS + s0 + 16 + r] = acc1[j] * scl;
    }
}

// -------- softmax over s for each (b,h); writes w transposed [b][s][h]
__global__ void __launch_bounds__(256) softmax_k(const float* __restrict__ sc,
        float* __restrict__ w)
{
    int bh = blockIdx.x;
    int b = bh >> 4, h = bh & 15;
    const float* row = sc + (size_t)bh * NS;
    __shared__ float sd[4];
    int tid = threadIdx.x;
    float mx = -3.4e38f;
    for (int s = tid; s < NS; s += 256) mx = fmaxf(mx, row[s]);
    for (int off = 32; off; off >>= 1) mx = fmaxf(mx, __shfl_down(mx, off));
    if ((tid & 63) == 0) sd[tid >> 6] = mx;
    __syncthreads();
    mx = fmaxf(fmaxf(sd[0], sd[1]), fmaxf(sd[2], sd[3]));
    __syncthreads();
    float sum = 0.f;
    for (int s = tid; s < NS; s += 256) sum += __expf(row[s] - mx);
    for (int off = 32; off; off >>= 1) sum += __shfl_down(sum, off);
    if ((tid & 63) == 0) sd[tid >> 6] = sum;
    __syncthreads();
    float total = sd[0] + sd[1] + sd[2] + sd[3];
    float inv = 1.f / total;
    for (int s = tid; s < NS; s += 256)
        w[((size_t)(b * NS + s)) * NH + h] = __expf(row[s] - mx) * inv;
}

// -------- pooled partial: pp[sc][b][h][d] over 512-s chunks
__global__ void __launch_bounds__(256) pool_k(const float* __restrict__ value,
        const float* __restrict__ w, float* __restrict__ pp)
{
    int b = blockIdx.x;
    int d = blockIdx.y * 256 + threadIdx.x;
    int s0 = blockIdx.z * 512;
    const float* vp = value + ((size_t)(b * NS + s0)) * ND + d;
    const float4* wp = (const float4*)(w + ((size_t)(b * NS + s0)) * NH);
    float4 a0 = {0,0,0,0}, a1 = {0,0,0,0}, a2 = {0,0,0,0}, a3 = {0,0,0,0};
    #pragma unroll 4
    for (int s = 0; s < 512; ++s) {
        float v = vp[(size_t)s * ND];
        float4 w0 = wp[s * 4 + 0], w1 = wp[s * 4 + 1];
        float4 w2 = wp[s * 4 + 2], w3 = wp[s * 4 + 3];
        a0.x += w0.x * v; a0.y += w0.y * v; a0.z += w0.z * v; a0.w += w0.w * v;
        a1.x += w1.x * v; a1.y += w1.y * v; a1.z += w1.z * v; a1.w += w1.w * v;
        a2.x += w2.x * v; a2.y += w2.y * v; a2.z += w2.z * v; a2.w += w2.w * v;
        a3.x += w3.x * v; a3.y += w3.y * v; a3.z += w3.z * v; a3.w += w3.w * v;
    }
    float* o = pp + ((size_t)((blockIdx.z * NB + b) * NH)) * 1024 + d;
    o[0*1024]=a0.x;  o[1*1024]=a0.y;  o[2*1024]=a0.z;  o[3*1024]=a0.w;
    o[4*1024]=a1.x;  o[5*1024]=a1.y;  o[6*1024]=a1.z;  o[7*1024]=a1.w;
    o[8*1024]=a2.x;  o[9*1024]=a2.y;  o[10*1024]=a2.z; o[11*1024]=a2.w;
    o[12*1024]=a3.x; o[13*1024]=a3.y; o[14*1024]=a3.z; o[15*1024]=a3.w;
}

// -------- m[b][h][d] = sum over 8 s-chunks
__global__ void __launch_bounds__(256) poolred_k(const float* __restrict__ pp,
        float* __restrict__ m)
{
    int i = blockIdx.x * 256 + threadIdx.x;   // 131072 total
    float s = 0.f;
    #pragma unroll
    for (int c = 0; c < 8; ++c) s += pp[(size_t)c * 131072 + i];
    m[i] = s;
}

// -------- layernorm: t = sum_{p<nprev} P[p][b][c] + bias[c] + add[b][c]; out = LN(t)*g+be
__global__ void __launch_bounds__(256) ln_k(const float* __restrict__ P, int nprev,
        const float* __restrict__ bias, const float* __restrict__ add,
        const float* __restrict__ g, const float* __restrict__ be,
        float* __restrict__ out)
{
    int b = blockIdx.x, tid = threadIdx.x;
    __shared__ float sd[4];
    int c = tid * 4;
    float4 t = *(const float4*)&bias[c];
    float4 a = *(const float4*)&add[(size_t)b * 1024 + c];
    t.x += a.x; t.y += a.y; t.z += a.z; t.w += a.w;
    #pragma unroll 4
    for (int p = 0; p < nprev; ++p) {
        float4 q = *(const float4*)&P[((size_t)(p * 8 + b)) * 1024 + c];
        t.x += q.x; t.y += q.y; t.z += q.z; t.w += q.w;
    }
    float loc = t.x + t.y + t.z + t.w;
    for (int off = 32; off; off >>= 1) loc += __shfl_down(loc, off);
    if ((tid & 63) == 0) sd[tid >> 6] = loc;
    __syncthreads();
    float mu = (sd[0] + sd[1] + sd[2] + sd[3]) * (1.f / 1024.f);
    __syncthreads();
    float vx = t.x - mu, vy = t.y - mu, vz = t.z - mu, vw = t.w - mu;
    float v = vx*vx + vy*vy + vz*vz + vw*vw;
    for (int off = 32; off; off >>= 1) v += __shfl_down(v, off);
    if ((tid & 63) == 0) sd[tid >> 6] = v;
    __syncthreads();
    float var = (sd[0] + sd[1] + sd[2] + sd[3]) * (1.f / 1024.f);
    float rs = rsqrtf(var + 1e-6f);
    float4 gg = *(const float4*)&g[c];
    float4 bb = *(const float4*)&be[c];
    float4 o;
    o.x = vx * rs * gg.x + bb.x;
    o.y = vy * rs * gg.y + bb.y;
    o.z = vz * rs * gg.z + bb.z;
    o.w = vw * rs * gg.w + bb.w;
    *(float4*)&out[(size_t)b * 1024 + c] = o;
}

extern "C" void kernel_launch(void* const* d_in, const int* in_sizes, int n_in,
                              void* d_out, int out_size, void* d_ws, size_t ws_size,
                              hipStream_t stream)
{
    const float* key   = (const float*)d_in[0];
    const float* value = (const float*)d_in[1];
    const float* dec   = (const float*)d_in[2];
    const float* Wq = (const float*)d_in[3];  const float* bq = (const float*)d_in[4];
    const float* Wk = (const float*)d_in[5];  /* bk cancels in softmax */
    const float* Wv = (const float*)d_in[7];  const float* bv = (const float*)d_in[8];
    const float* Wo = (const float*)d_in[9];  const float* bo = (const float*)d_in[10];
    const float* W1 = (const float*)d_in[11]; const float* b1 = (const float*)d_in[12];
    const float* W2 = (const float*)d_in[13]; const float* b2 = (const float*)d_in[14];
    const float* g2 = (const float*)d_in[15]; const float* be2 = (const float*)d_in[16];
    const float* gf = (const float*)d_in[17]; const float* bef = (const float*)d_in[18];

    float* ws = (float*)d_ws;
    float* A    = ws;                  // 1MB slot  [<=32][8][1024]
    float* Bp   = A    + 262144;       // 2MB slot  [<=64][8][1024]
    float* ff1p = Bp   + 524288;       // [16][8][4096]
    float* plp  = ff1p + 524288;       // [8][8][16][1024]
    float* scb  = plp  + 1048576;      // [8][16][4096]
    float* wsh  = scb  + 524288;       // [8][4096][16]
    float* mb   = wsh  + 524288;       // [8][16][1024]
    float* xbuf = mb   + 131072;       // [8][1024]
    unsigned short* u16 = (unsigned short*)(xbuf + 8192);   // [8][16][1024] bf16

    dim3 blk(256);

    // prologue chain: V1 = dec@Wv ; t1 = (V1+bv)@Wo ; Q2 = (t1+bo)@Wq
    mv8_k<<<dim3(4,32), blk, 0, stream>>>(dec, nullptr, 0, nullptr, 0, 0, Wv, 1024, 1024, 32, A);
    mv8_k<<<dim3(4,32), blk, 0, stream>>>(nullptr, A,  32, bv, 0, 0, Wo, 1024, 1024, 32, Bp);
    mv8_k<<<dim3(4,32), blk, 0, stream>>>(nullptr, Bp, 32, bo, 0, 0, Wq, 1024, 1024, 32, A);

    // u[b,h,:] = Wk[:,head_h] @ (Q2[b,head_h]+bq)
    u_k<<<dim3(128,4), blk, 0, stream>>>(A, bq, Wk, u16);

    // scores over key, softmax, pool over value
    scores_k<<<dim3(8,32), blk, 0, stream>>>(key, u16, scb);
    softmax_k<<<dim3(128), blk, 0, stream>>>(scb, wsh);
    pool_k<<<dim3(8,4,8), blk, 0, stream>>>(value, wsh, plp);
    poolred_k<<<dim3(512), blk, 0, stream>>>(plp, mb);

    // av = m@Wv(per-head) ; t2 = (av+bv)@Wo ; x = LN(t2+bo+dec)
    mv8_k<<<dim3(4,32), blk, 0, stream>>>(mb, nullptr, 0, nullptr, 0, 1, Wv, 1024, 1024, 32, Bp);
    mv8_k<<<dim3(4,32), blk, 0, stream>>>(nullptr, Bp, 32, bv, 0, 0, Wo, 1024, 1024, 32, A);
    ln_k<<<dim3(8), blk, 0, stream>>>(A, 32, bo, dec, g2, be2, xbuf);

    // ff: relu(x@W1+b1)@W2 + b2 + x, then final LN
    mv8_k<<<dim3(16,16), blk, 0, stream>>>(xbuf, nullptr, 0, nullptr, 0, 0, W1, 1024, 4096, 64, ff1p);
    mv8_k<<<dim3(4,64),  blk, 0, stream>>>(nullptr, ff1p, 16, b1, 1, 0, W2, 4096, 1024, 64, Bp);
    ln_k<<<dim3(8), blk, 0, stream>>>(Bp, 64, b2, xbuf, gf, bef, (float*)d_out);

    (void)in_sizes; (void)n_in; (void)out_size; (void)ws_size;
}

// Round 3
// 198.001 us; speedup vs baseline: 1.9250x; 1.2508x over previous
//
#include <hip/hip_runtime.h>
#include <hip/hip_bf16.h>

#define NB 8
#define NS 4096
#define ND 1024
#define NH 16
#define NF 4096

typedef __attribute__((ext_vector_type(8))) short s16x8;
typedef __attribute__((ext_vector_type(4))) float f32x4;

__device__ __forceinline__ short f2bfs(float x) {
    __hip_bfloat16 h = __float2bfloat16(x);
    return *reinterpret_cast<short*>(&h);
}

__device__ __forceinline__ s16x8 pack8(float4 a, float4 b) {
    s16x8 r;
    r[0]=f2bfs(a.x); r[1]=f2bfs(a.y); r[2]=f2bfs(a.z); r[3]=f2bfs(a.w);
    r[4]=f2bfs(b.x); r[5]=f2bfs(b.y); r[6]=f2bfs(b.z); r[7]=f2bfs(b.w);
    return r;
}

// -------- matvec partial: Pout[kp][b][c] = sum_{k in chunk} x[b][k]*W[k][c]
// x reduced vector [8][K] (or per-head [8][16][1024]); 8 batches per thread.
template<int KC, int PER_HEAD>
__global__ void __launch_bounds__(256) mv_t(const float* __restrict__ x,
        const float* __restrict__ W, int K, int Cout, float* __restrict__ Pout)
{
    __shared__ float xs[1024];
    int tid = threadIdx.x;
    int c = blockIdx.x * 256 + tid;
    int k0 = blockIdx.y * KC;
    int base = 0;
    if (PER_HEAD) {
        int wv = tid >> 6, lane = tid & 63;
        int h = (blockIdx.x * 256 + wv * 64) >> 6;     // uniform per wave
        base = wv * KC * 8;
        for (int i = lane; i < KC * 8; i += 64) {
            int k = i >> 3, b = i & 7;
            xs[base + i] = x[((size_t)(b * NH + h)) * 1024 + k0 + k];
        }
    } else {
        for (int i = tid; i < KC * 8; i += 256) {
            int k = i >> 3, b = i & 7;
            xs[i] = x[(size_t)b * K + k0 + k];
        }
    }
    __syncthreads();
    const float* Wp = W + (size_t)k0 * Cout + c;
    float acc[8] = {0,0,0,0,0,0,0,0};
    #pragma unroll
    for (int k = 0; k < KC; ++k) {
        float wv = Wp[(size_t)k * Cout];
        float4 x0 = *(const float4*)&xs[base + k * 8];
        float4 x1 = *(const float4*)&xs[base + k * 8 + 4];
        acc[0] += x0.x * wv; acc[1] += x0.y * wv; acc[2] += x0.z * wv; acc[3] += x0.w * wv;
        acc[4] += x1.x * wv; acc[5] += x1.y * wv; acc[6] += x1.z * wv; acc[7] += x1.w * wv;
    }
    float* op = Pout + ((size_t)blockIdx.y * 8) * Cout + c;
    #pragma unroll
    for (int b = 0; b < 8; ++b) op[(size_t)b * Cout] = acc[b];
}

// -------- reduce partials: out[b][c] = act(sum_p P[p][b][c] + bias[c])
__global__ void __launch_bounds__(256) red_k(const float* __restrict__ P, int np,
        const float* __restrict__ bias, int relu, int C, float* __restrict__ out)
{
    int b = blockIdx.x, c = blockIdx.y * 256 + threadIdx.x;
    float t = bias[c];
    #pragma unroll 8
    for (int p = 0; p < np; ++p) t += P[((size_t)(p * 8 + b)) * C + c];
    if (relu) t = fmaxf(t, 0.f);
    out[(size_t)b * C + c] = t;
}

// -------- u[b,h,d] = sum_{j<64} Wk[d][h*64+j] * q2r[b][h*64+j], bf16 out
__global__ void __launch_bounds__(256) u_k(const float* __restrict__ q2r,
        const float* __restrict__ Wk, unsigned short* __restrict__ u16)
{
    int bh = blockIdx.x;               // b*16+h
    int b = bh >> 4, h = bh & 15;
    int lane = threadIdx.x & 63, wv = threadIdx.x >> 6;
    int cc = h * 64 + lane;
    float q = q2r[(size_t)b * 1024 + cc];
    int dbase = blockIdx.y * 256;
    #pragma unroll 4
    for (int d = dbase + wv; d < dbase + 256; d += 4) {
        float v = Wk[(size_t)d * 1024 + cc] * q;
        for (int off = 32; off; off >>= 1) v += __shfl_down(v, off);
        if (lane == 0) u16[(size_t)bh * 1024 + d] = (unsigned short)f2bfs(v);
    }
}

// -------- scores[b][h][s] = (key[b,s,:] . u[b,h,:]) / 32 ; one 16-tile per wave
__global__ void __launch_bounds__(256) scores_k(const float* __restrict__ key,
        const unsigned short* __restrict__ u16, float* __restrict__ sc)
{
    __shared__ __align__(16) unsigned short ul[16][1032];
    int b = blockIdx.x, tid = threadIdx.x;
    const uint4* src = (const uint4*)(u16 + (size_t)b * NH * 1024);
    for (int v = tid; v < 2048; v += 256) {
        int h = v >> 7, col = (v & 127) * 8;
        *(uint4*)&ul[h][col] = src[v];
    }
    __syncthreads();
    int lane = tid & 63, wv = tid >> 6;
    int r = lane & 15, g = lane >> 4;
    int s0 = blockIdx.y * 64 + wv * 16;
    const float* kp0 = key + ((size_t)(b * NS + s0 + r)) * ND + g * 8;
    f32x4 acc = {0.f, 0.f, 0.f, 0.f};
    float4 c0, c1, c2, c3, n0, n1, n2, n3;
    c0 = *(const float4*)(kp0);      c1 = *(const float4*)(kp0 + 4);
    c2 = *(const float4*)(kp0 + 32); c3 = *(const float4*)(kp0 + 36);
    #pragma unroll
    for (int k = 0; k < 1024; k += 64) {
        if (k + 64 < 1024) {
            const float* p = kp0 + k + 64;
            n0 = *(const float4*)(p);      n1 = *(const float4*)(p + 4);
            n2 = *(const float4*)(p + 32); n3 = *(const float4*)(p + 36);
        }
        s16x8 a0 = *(const s16x8*)&ul[r][k + g * 8];
        acc = __builtin_amdgcn_mfma_f32_16x16x32_bf16(a0, pack8(c0, c1), acc, 0, 0, 0);
        s16x8 a1 = *(const s16x8*)&ul[r][k + 32 + g * 8];
        acc = __builtin_amdgcn_mfma_f32_16x16x32_bf16(a1, pack8(c2, c3), acc, 0, 0, 0);
        c0 = n0; c1 = n1; c2 = n2; c3 = n3;
    }
    const float scl = 1.f / 32.f;   // 1/sqrt(1024)
    #pragma unroll
    for (int j = 0; j < 4; ++j) {
        int h = g * 4 + j;
        sc[((size_t)(b * NH + h)) * NS + s0 + r] = acc[j] * scl;
    }
}

// -------- softmax over s for each (b,h); writes w transposed [b][s][h]
__global__ void __launch_bounds__(256) softmax_k(const float* __restrict__ sc,
        float* __restrict__ w)
{
    int bh = blockIdx.x;
    int b = bh >> 4, h = bh & 15;
    const float* row = sc + (size_t)bh * NS;
    __shared__ float sd[4];
    int tid = threadIdx.x;
    float mx = -3.4e38f;
    for (int s = tid; s < NS; s += 256) mx = fmaxf(mx, row[s]);
    for (int off = 32; off; off >>= 1) mx = fmaxf(mx, __shfl_down(mx, off));
    if ((tid & 63) == 0) sd[tid >> 6] = mx;
    __syncthreads();
    mx = fmaxf(fmaxf(sd[0], sd[1]), fmaxf(sd[2], sd[3]));
    __syncthreads();
    float sum = 0.f;
    for (int s = tid; s < NS; s += 256) sum += __expf(row[s] - mx);
    for (int off = 32; off; off >>= 1) sum += __shfl_down(sum, off);
    if ((tid & 63) == 0) sd[tid >> 6] = sum;
    __syncthreads();
    float total = sd[0] + sd[1] + sd[2] + sd[3];
    float inv = 1.f / total;
    for (int s = tid; s < NS; s += 256)
        w[((size_t)(b * NS + s)) * NH + h] = __expf(row[s] - mx) * inv;
}

// -------- pooled partial over 256-s chunks, 8-deep rolling prefetch
__global__ void __launch_bounds__(256) pool_k(const float* __restrict__ value,
        const float* __restrict__ w, float* __restrict__ pp)
{
    int b = blockIdx.x;
    int d = blockIdx.y * 256 + threadIdx.x;
    int s0 = blockIdx.z * 256;
    const float* vp = value + ((size_t)(b * NS + s0)) * ND + d;
    const float* wp = w + ((size_t)(b * NS + s0)) * NH;
    float acc[16];
    #pragma unroll
    for (int h = 0; h < 16; ++h) acc[h] = 0.f;
    float v[8], nv[8];
    #pragma unroll
    for (int j = 0; j < 8; ++j) v[j] = vp[(size_t)j * ND];
    for (int s = 0; s < 256; s += 8) {
        if (s + 8 < 256) {
            #pragma unroll
            for (int j = 0; j < 8; ++j) nv[j] = vp[(size_t)(s + 8 + j) * ND];
        }
        #pragma unroll
        for (int j = 0; j < 8; ++j) {
            const float4* wq = (const float4*)(wp + (size_t)(s + j) * NH);
            float4 w0 = wq[0], w1 = wq[1], w2 = wq[2], w3 = wq[3];
            float vv = v[j];
            acc[0]  += w0.x * vv; acc[1]  += w0.y * vv; acc[2]  += w0.z * vv; acc[3]  += w0.w * vv;
            acc[4]  += w1.x * vv; acc[5]  += w1.y * vv; acc[6]  += w1.z * vv; acc[7]  += w1.w * vv;
            acc[8]  += w2.x * vv; acc[9]  += w2.y * vv; acc[10] += w2.z * vv; acc[11] += w2.w * vv;
            acc[12] += w3.x * vv; acc[13] += w3.y * vv; acc[14] += w3.z * vv; acc[15] += w3.w * vv;
        }
        #pragma unroll
        for (int j = 0; j < 8; ++j) v[j] = nv[j];
    }
    float* o = pp + ((size_t)((blockIdx.z * NB + b) * NH)) * 1024 + d;
    #pragma unroll
    for (int h = 0; h < 16; ++h) o[(size_t)h * 1024] = acc[h];
}

// -------- m[b][h][d] = sum over 16 s-chunks
__global__ void __launch_bounds__(256) poolred_k(const float* __restrict__ pp,
        float* __restrict__ m)
{
    int i = blockIdx.x * 256 + threadIdx.x;   // 131072 total
    float s = 0.f;
    #pragma unroll
    for (int c = 0; c < 16; ++c) s += pp[(size_t)c * 131072 + i];
    m[i] = s;
}

// -------- layernorm: t = tin[b][c] + add[b][c]; out = LN(t)*g+be
__global__ void __launch_bounds__(256) ln2_k(const float* __restrict__ tin,
        const float* __restrict__ add, const float* __restrict__ g,
        const float* __restrict__ be, float* __restrict__ out)
{
    int b = blockIdx.x, tid = threadIdx.x;
    __shared__ float sd[4];
    int c = tid * 4;
    float4 t = *(const float4*)&tin[(size_t)b * 1024 + c];
    float4 a = *(const float4*)&add[(size_t)b * 1024 + c];
    t.x += a.x; t.y += a.y; t.z += a.z; t.w += a.w;
    float loc = t.x + t.y + t.z + t.w;
    for (int off = 32; off; off >>= 1) loc += __shfl_down(loc, off);
    if ((tid & 63) == 0) sd[tid >> 6] = loc;
    __syncthreads();
    float mu = (sd[0] + sd[1] + sd[2] + sd[3]) * (1.f / 1024.f);
    __syncthreads();
    float vx = t.x - mu, vy = t.y - mu, vz = t.z - mu, vw = t.w - mu;
    float v = vx*vx + vy*vy + vz*vz + vw*vw;
    for (int off = 32; off; off >>= 1) v += __shfl_down(v, off);
    if ((tid & 63) == 0) sd[tid >> 6] = v;
    __syncthreads();
    float var = (sd[0] + sd[1] + sd[2] + sd[3]) * (1.f / 1024.f);
    float rs = rsqrtf(var + 1e-6f);
    float4 gg = *(const float4*)&g[c];
    float4 bb = *(const float4*)&be[c];
    float4 o;
    o.x = vx * rs * gg.x + bb.x;
    o.y = vy * rs * gg.y + bb.y;
    o.z = vz * rs * gg.z + bb.z;
    o.w = vw * rs * gg.w + bb.w;
    *(float4*)&out[(size_t)b * 1024 + c] = o;
}

extern "C" void kernel_launch(void* const* d_in, const int* in_sizes, int n_in,
                              void* d_out, int out_size, void* d_ws, size_t ws_size,
                              hipStream_t stream)
{
    const float* key   = (const float*)d_in[0];
    const float* value = (const float*)d_in[1];
    const float* dec   = (const float*)d_in[2];
    const float* Wq = (const float*)d_in[3];  const float* bq = (const float*)d_in[4];
    const float* Wk = (const float*)d_in[5];  /* bk cancels in softmax */
    const float* Wv = (const float*)d_in[7];  const float* bv = (const float*)d_in[8];
    const float* Wo = (const float*)d_in[9];  const float* bo = (const float*)d_in[10];
    const float* W1 = (const float*)d_in[11]; const float* b1 = (const float*)d_in[12];
    const float* W2 = (const float*)d_in[13]; const float* b2 = (const float*)d_in[14];
    const float* g2 = (const float*)d_in[15]; const float* be2 = (const float*)d_in[16];
    const float* gf = (const float*)d_in[17]; const float* bef = (const float*)d_in[18];

    float* ws = (float*)d_ws;
    float* scb = ws;                                        // [8][16][4096]
    float* wsh = scb + 524288;                              // [8][4096][16]
    unsigned short* u16 = (unsigned short*)(wsh + 524288);  // [8][16][1024] bf16
    float* sv   = wsh + 524288 + 32768;
    float* v1r  = sv;                // [8][1024]
    float* t1r  = v1r + 8192;
    float* q2r  = t1r + 8192;
    float* avr  = q2r + 8192;
    float* t2r  = avr + 8192;
    float* xbuf = t2r + 8192;
    float* ff2r = xbuf + 8192;
    float* xff  = ff2r + 8192;       // [8][4096]
    float* mb   = xff + 32768;       // [8][16][1024]
    float* BIG  = mb + 131072;       // 2097152 floats, aliased phase-wise
    float* P1   = BIG;               // [64][8][1024]
    float* P2   = BIG + 524288;      // [64][8][1024]
    float* plp  = BIG;               // [16][8][16][1024]
    float* Pff1 = BIG;               // [32][8][4096]
    float* Pff2 = BIG + 1048576;     // [128][8][1024]

    dim3 blk(256);

    // prologue chain: v1 = dec@Wv+bv ; t1 = v1@Wo+bo ; q2 = t1@Wq+bq
    mv_t<16,0><<<dim3(4,64), blk, 0, stream>>>(dec, Wv, 1024, 1024, P1);
    red_k<<<dim3(8,4), blk, 0, stream>>>(P1, 64, bv, 0, 1024, v1r);
    mv_t<16,0><<<dim3(4,64), blk, 0, stream>>>(v1r, Wo, 1024, 1024, P2);
    red_k<<<dim3(8,4), blk, 0, stream>>>(P2, 64, bo, 0, 1024, t1r);
    mv_t<16,0><<<dim3(4,64), blk, 0, stream>>>(t1r, Wq, 1024, 1024, P1);
    red_k<<<dim3(8,4), blk, 0, stream>>>(P1, 64, bq, 0, 1024, q2r);

    // u[b,h,:] = Wk[:,head_h] @ q2[b,head_h]
    u_k<<<dim3(128,4), blk, 0, stream>>>(q2r, Wk, u16);

    // scores over key, softmax, pool over value
    scores_k<<<dim3(8,64), blk, 0, stream>>>(key, u16, scb);
    softmax_k<<<dim3(128), blk, 0, stream>>>(scb, wsh);
    pool_k<<<dim3(8,4,16), blk, 0, stream>>>(value, wsh, plp);
    poolred_k<<<dim3(512), blk, 0, stream>>>(plp, mb);

    // av = m@Wv(per-head)+bv ; t2 = av@Wo+bo ; x = LN(t2+dec)
    mv_t<16,1><<<dim3(4,64), blk, 0, stream>>>(mb, Wv, 1024, 1024, P1);
    red_k<<<dim3(8,4), blk, 0, stream>>>(P1, 64, bv, 0, 1024, avr);
    mv_t<16,0><<<dim3(4,64), blk, 0, stream>>>(avr, Wo, 1024, 1024, P2);
    red_k<<<dim3(8,4), blk, 0, stream>>>(P2, 64, bo, 0, 1024, t2r);
    ln2_k<<<dim3(8), blk, 0, stream>>>(t2r, dec, g2, be2, xbuf);

    // ff: xff = relu(x@W1+b1) ; ff2 = xff@W2+b2 ; out = LN(ff2+x)
    mv_t<32,0><<<dim3(16,32), blk, 0, stream>>>(xbuf, W1, 1024, 4096, Pff1);
    red_k<<<dim3(8,16), blk, 0, stream>>>(Pff1, 32, b1, 1, 4096, xff);
    mv_t<32,0><<<dim3(4,128), blk, 0, stream>>>(xff, W2, 4096, 1024, Pff2);
    red_k<<<dim3(8,4), blk, 0, stream>>>(Pff2, 128, b2, 0, 1024, ff2r);
    ln2_k<<<dim3(8), blk, 0, stream>>>(ff2r, xbuf, gf, bef, (float*)d_out);

    (void)in_sizes; (void)n_in; (void)out_size; (void)ws_size;
}

// Round 4
// 180.885 us; speedup vs baseline: 2.1072x; 1.0946x over previous
//
#include <hip/hip_runtime.h>
#include <hip/hip_bf16.h>

#define NB 8
#define NS 4096
#define ND 1024
#define NH 16
#define NF 4096

typedef __attribute__((ext_vector_type(8))) short s16x8;
typedef __attribute__((ext_vector_type(4))) float f32x4;

__device__ __forceinline__ short f2bfs(float x) {
    __hip_bfloat16 h = __float2bfloat16(x);
    return *reinterpret_cast<short*>(&h);
}

__device__ __forceinline__ s16x8 pack8(float4 a, float4 b) {
    s16x8 r;
    r[0]=f2bfs(a.x); r[1]=f2bfs(a.y); r[2]=f2bfs(a.z); r[3]=f2bfs(a.w);
    r[4]=f2bfs(b.x); r[5]=f2bfs(b.y); r[6]=f2bfs(b.z); r[7]=f2bfs(b.w);
    return r;
}

// ===== matvec from dense vector x[8][K]: Pout[(kp*8+b)*Cout+c] = sum_k x[b][k0+k]*W[k0+k][c]
template<int KC>
__global__ void __launch_bounds__(256) mvV_k(const float* __restrict__ x,
        const float* __restrict__ W, int K, int Cout, float* __restrict__ Pout)
{
    __shared__ float xs[KC * 8];
    int tid = threadIdx.x;
    int c = blockIdx.x * 256 + tid;
    int k0 = blockIdx.y * KC;
    for (int i = tid; i < KC * 8; i += 256) {
        int k = i >> 3, b = i & 7;
        xs[i] = x[(size_t)b * K + k0 + k];
    }
    __syncthreads();
    const float* Wp = W + (size_t)k0 * Cout + c;
    float acc[8] = {0,0,0,0,0,0,0,0};
    #pragma unroll 16
    for (int k = 0; k < KC; ++k) {
        float wv = Wp[(size_t)k * Cout];
        float4 x0 = *(const float4*)&xs[k * 8];
        float4 x1 = *(const float4*)&xs[k * 8 + 4];
        acc[0] += x0.x * wv; acc[1] += x0.y * wv; acc[2] += x0.z * wv; acc[3] += x0.w * wv;
        acc[4] += x1.x * wv; acc[5] += x1.y * wv; acc[6] += x1.z * wv; acc[7] += x1.w * wv;
    }
    float* op = Pout + ((size_t)blockIdx.y * 8) * Cout + c;
    #pragma unroll
    for (int b = 0; b < 8; ++b) op[(size_t)b * Cout] = acc[b];
}

// ===== matvec from NP partials: x[b][k] = act(sum_p P[(p*8+b)*K+k] + bias[k])
template<int KC, int NP, int RELU>
__global__ void __launch_bounds__(256) mvP_k(const float* __restrict__ P,
        const float* __restrict__ bias, const float* __restrict__ W,
        int K, int Cout, float* __restrict__ Pout)
{
    __shared__ float xs[KC * 8];
    int tid = threadIdx.x;
    int c = blockIdx.x * 256 + tid;
    int k0 = blockIdx.y * KC;
    for (int i = tid; i < KC * 8; i += 256) {
        int b = i / KC, k = i % KC;          // k minor: contiguous partial reads
        float t = bias[k0 + k];
        #pragma unroll 8
        for (int p = 0; p < NP; ++p) t += P[((size_t)(p * 8 + b)) * K + k0 + k];
        if (RELU) t = fmaxf(t, 0.f);
        xs[k * 8 + b] = t;
    }
    __syncthreads();
    const float* Wp = W + (size_t)k0 * Cout + c;
    float acc[8] = {0,0,0,0,0,0,0,0};
    #pragma unroll 16
    for (int k = 0; k < KC; ++k) {
        float wv = Wp[(size_t)k * Cout];
        float4 x0 = *(const float4*)&xs[k * 8];
        float4 x1 = *(const float4*)&xs[k * 8 + 4];
        acc[0] += x0.x * wv; acc[1] += x0.y * wv; acc[2] += x0.z * wv; acc[3] += x0.w * wv;
        acc[4] += x1.x * wv; acc[5] += x1.y * wv; acc[6] += x1.z * wv; acc[7] += x1.w * wv;
    }
    float* op = Pout + ((size_t)blockIdx.y * 8) * Cout + c;
    #pragma unroll
    for (int b = 0; b < 8; ++b) op[(size_t)b * Cout] = acc[b];
}

// ===== per-head matvec with fused chunk reduce: x[b][h][k] = sum_ch plp[((ch*8+b)*16+h)*1024+k]
template<int KC, int NCH>
__global__ void __launch_bounds__(256) mvH_k(const float* __restrict__ plp,
        const float* __restrict__ W, float* __restrict__ Pout)
{
    __shared__ float xs[4 * KC * 8];
    int tid = threadIdx.x, lane = tid & 63, wv = tid >> 6;
    int c = blockIdx.x * 256 + tid;
    int k0 = blockIdx.y * KC;
    int h = (blockIdx.x * 256 + wv * 64) >> 6;   // wave-uniform head
    for (int i = lane; i < 8 * KC; i += 64) {
        int b = i / KC, k = i % KC;
        float t = 0.f;
        #pragma unroll 8
        for (int ch = 0; ch < NCH; ++ch)
            t += plp[((size_t)((ch * 8 + b) * 16 + h)) * 1024 + k0 + k];
        xs[wv * 8 * KC + k * 8 + b] = t;
    }
    __syncthreads();
    const float* Wp = W + (size_t)k0 * 1024 + c;
    float acc[8] = {0,0,0,0,0,0,0,0};
    #pragma unroll 16
    for (int k = 0; k < KC; ++k) {
        float wvv = Wp[(size_t)k * 1024];
        float4 x0 = *(const float4*)&xs[wv * 8 * KC + k * 8];
        float4 x1 = *(const float4*)&xs[wv * 8 * KC + k * 8 + 4];
        acc[0] += x0.x * wvv; acc[1] += x0.y * wvv; acc[2] += x0.z * wvv; acc[3] += x0.w * wvv;
        acc[4] += x1.x * wvv; acc[5] += x1.y * wvv; acc[6] += x1.z * wvv; acc[7] += x1.w * wvv;
    }
    float* op = Pout + ((size_t)blockIdx.y * 8) * 1024 + c;
    #pragma unroll
    for (int b = 0; b < 8; ++b) op[(size_t)b * 1024] = acc[b];
}

// ===== u[b,h,d] = sum_cc Wk[d][h*64+cc] * q[b][h*64+cc]; q from 64 partials + bq
__global__ void __launch_bounds__(256) u_k(const float* __restrict__ P,
        const float* __restrict__ bq, const float* __restrict__ Wk,
        unsigned short* __restrict__ u16)
{
    int bh = blockIdx.x;               // b*16+h
    int b = bh >> 4, h = bh & 15;
    int lane = threadIdx.x & 63, wv = threadIdx.x >> 6;
    int cc = h * 64 + lane;
    float q = bq[cc];
    #pragma unroll 8
    for (int p = 0; p < 64; ++p) q += P[((size_t)(p * 8 + b)) * 1024 + cc];
    int dbase = blockIdx.y * 256;
    #pragma unroll 4
    for (int d = dbase + wv; d < dbase + 256; d += 4) {
        float v = Wk[(size_t)d * 1024 + cc] * q;
        for (int off = 32; off; off >>= 1) v += __shfl_down(v, off);
        if (lane == 0) u16[(size_t)bh * 1024 + d] = (unsigned short)f2bfs(v);
    }
}

// ===== scores[b][h][s] = (key[b,s,:] . u[b,h,:]) / 32 ; one 16-tile per wave
__global__ void __launch_bounds__(256) scores_k(const float* __restrict__ key,
        const unsigned short* __restrict__ u16, float* __restrict__ sc)
{
    __shared__ __align__(16) unsigned short ul[16][1032];
    int b = blockIdx.x, tid = threadIdx.x;
    const uint4* src = (const uint4*)(u16 + (size_t)b * NH * 1024);
    for (int v = tid; v < 2048; v += 256) {
        int h = v >> 7, col = (v & 127) * 8;
        *(uint4*)&ul[h][col] = src[v];
    }
    __syncthreads();
    int lane = tid & 63, wv = tid >> 6;
    int r = lane & 15, g = lane >> 4;
    int s0 = blockIdx.y * 64 + wv * 16;
    const float* kp0 = key + ((size_t)(b * NS + s0 + r)) * ND + g * 8;
    f32x4 acc = {0.f, 0.f, 0.f, 0.f};
    float4 c0, c1, c2, c3, n0, n1, n2, n3;
    c0 = *(const float4*)(kp0);      c1 = *(const float4*)(kp0 + 4);
    c2 = *(const float4*)(kp0 + 32); c3 = *(const float4*)(kp0 + 36);
    #pragma unroll
    for (int k = 0; k < 1024; k += 64) {
        if (k + 64 < 1024) {
            const float* p = kp0 + k + 64;
            n0 = *(const float4*)(p);      n1 = *(const float4*)(p + 4);
            n2 = *(const float4*)(p + 32); n3 = *(const float4*)(p + 36);
        }
        s16x8 a0 = *(const s16x8*)&ul[r][k + g * 8];
        acc = __builtin_amdgcn_mfma_f32_16x16x32_bf16(a0, pack8(c0, c1), acc, 0, 0, 0);
        s16x8 a1 = *(const s16x8*)&ul[r][k + 32 + g * 8];
        acc = __builtin_amdgcn_mfma_f32_16x16x32_bf16(a1, pack8(c2, c3), acc, 0, 0, 0);
        c0 = n0; c1 = n1; c2 = n2; c3 = n3;
    }
    const float scl = 1.f / 32.f;   // 1/sqrt(1024)
    #pragma unroll
    for (int j = 0; j < 4; ++j) {
        int h = g * 4 + j;
        sc[((size_t)(b * NH + h)) * NS + s0 + r] = acc[j] * scl;
    }
}

// ===== per-(b,h) row max and 1/sum(exp) over 4096 scores
__global__ void __launch_bounds__(256) smred_k(const float* __restrict__ sc,
        float* __restrict__ minv)
{
    int bh = blockIdx.x, tid = threadIdx.x;
    const f32x4* row = (const f32x4*)(sc + (size_t)bh * NS);
    __shared__ float sd[4];
    f32x4 x0 = row[tid], x1 = row[256 + tid], x2 = row[512 + tid], x3 = row[768 + tid];
    float m = fmaxf(fmaxf(fmaxf(x0[0], x0[1]), fmaxf(x0[2], x0[3])),
                    fmaxf(fmaxf(x1[0], x1[1]), fmaxf(x1[2], x1[3])));
    m = fmaxf(m, fmaxf(fmaxf(fmaxf(x2[0], x2[1]), fmaxf(x2[2], x2[3])),
                       fmaxf(fmaxf(x3[0], x3[1]), fmaxf(x3[2], x3[3]))));
    for (int off = 32; off; off >>= 1) m = fmaxf(m, __shfl_down(m, off));
    if ((tid & 63) == 0) sd[tid >> 6] = m;
    __syncthreads();
    float mx = fmaxf(fmaxf(sd[0], sd[1]), fmaxf(sd[2], sd[3]));
    __syncthreads();
    float s = 0.f;
    #pragma unroll
    for (int j = 0; j < 4; ++j) s += __expf(x0[j] - mx) + __expf(x1[j] - mx)
                                   + __expf(x2[j] - mx) + __expf(x3[j] - mx);
    for (int off = 32; off; off >>= 1) s += __shfl_down(s, off);
    if ((tid & 63) == 0) sd[tid >> 6] = s;
    __syncthreads();
    if (tid == 0) {
        minv[bh * 2]     = mx;
        minv[bh * 2 + 1] = 1.f / (sd[0] + sd[1] + sd[2] + sd[3]);
    }
}

// ===== pooled partial with fused softmax: plp[((sc*8+b)*16+h)*1024+d]
//       = sum_{s in 128-chunk} exp(scb-mx)*inv * value[b][s][d]
__global__ void __launch_bounds__(256) pool_k(const float* __restrict__ value,
        const float* __restrict__ scb, const float* __restrict__ minv,
        float* __restrict__ plp)
{
    __shared__ float pl[16][128];
    int b = blockIdx.x, sc4 = blockIdx.y, tid = threadIdx.x;
    int s0 = sc4 * 128;
    for (int i = tid; i < 2048; i += 256) {
        int h = i >> 7, si = i & 127;
        float mx  = minv[(b * 16 + h) * 2];
        float inv = minv[(b * 16 + h) * 2 + 1];
        pl[h][si] = __expf(scb[((size_t)(b * 16 + h)) * NS + s0 + si] - mx) * inv;
    }
    __syncthreads();
    const float* vp = value + ((size_t)(b * NS + s0)) * ND + tid * 4;
    f32x4 acc[16];
    #pragma unroll
    for (int h = 0; h < 16; ++h) acc[h] = (f32x4){0.f, 0.f, 0.f, 0.f};
    f32x4 v0,v1,v2,v3,v4,v5,v6,v7;
    v0 = *(const f32x4*)(vp + 0*ND); v1 = *(const f32x4*)(vp + 1*ND);
    v2 = *(const f32x4*)(vp + 2*ND); v3 = *(const f32x4*)(vp + 3*ND);
    v4 = *(const f32x4*)(vp + 4*ND); v5 = *(const f32x4*)(vp + 5*ND);
    v6 = *(const f32x4*)(vp + 6*ND); v7 = *(const f32x4*)(vp + 7*ND);
    for (int g = 0; g < 128; g += 8) {
        f32x4 n0,n1,n2,n3,n4,n5,n6,n7;
        if (g + 8 < 128) {
            const float* p = vp + (size_t)(g + 8) * ND;
            n0 = *(const f32x4*)(p + 0*ND); n1 = *(const f32x4*)(p + 1*ND);
            n2 = *(const f32x4*)(p + 2*ND); n3 = *(const f32x4*)(p + 3*ND);
            n4 = *(const f32x4*)(p + 4*ND); n5 = *(const f32x4*)(p + 5*ND);
            n6 = *(const f32x4*)(p + 6*ND); n7 = *(const f32x4*)(p + 7*ND);
        }
        #pragma unroll
        for (int h = 0; h < 16; ++h) {
            f32x4 wa = *(const f32x4*)&pl[h][g];
            f32x4 wb = *(const f32x4*)&pl[h][g + 4];
            acc[h] += v0 * wa[0] + v1 * wa[1] + v2 * wa[2] + v3 * wa[3]
                    + v4 * wb[0] + v5 * wb[1] + v6 * wb[2] + v7 * wb[3];
        }
        v0 = n0; v1 = n1; v2 = n2; v3 = n3;
        v4 = n4; v5 = n5; v6 = n6; v7 = n7;
    }
    float* o = plp + ((size_t)((sc4 * 8 + b) * 16)) * 1024 + tid * 4;
    #pragma unroll
    for (int h = 0; h < 16; ++h) *(f32x4*)(o + (size_t)h * 1024) = acc[h];
}

// ===== layernorm over partials: t = sum_{p<np} P + bias + add; out = LN(t)*g+be
__global__ void __launch_bounds__(256) lnp_k(const float* __restrict__ P, int np,
        const float* __restrict__ bias, const float* __restrict__ add,
        const float* __restrict__ g, const float* __restrict__ be,
        float* __restrict__ out)
{
    int b = blockIdx.x, tid = threadIdx.x;
    __shared__ float sd[4];
    int c = tid * 4;
    f32x4 t = *(const f32x4*)&bias[c];
    t += *(const f32x4*)&add[(size_t)b * 1024 + c];
    #pragma unroll 8
    for (int p = 0; p < np; ++p)
        t += *(const f32x4*)&P[((size_t)(p * 8 + b)) * 1024 + c];
    float loc = t[0] + t[1] + t[2] + t[3];
    for (int off = 32; off; off >>= 1) loc += __shfl_down(loc, off);
    if ((tid & 63) == 0) sd[tid >> 6] = loc;
    __syncthreads();
    float mu = (sd[0] + sd[1] + sd[2] + sd[3]) * (1.f / 1024.f);
    __syncthreads();
    f32x4 d = t - mu;
    float v = d[0]*d[0] + d[1]*d[1] + d[2]*d[2] + d[3]*d[3];
    for (int off = 32; off; off >>= 1) v += __shfl_down(v, off);
    if ((tid & 63) == 0) sd[tid >> 6] = v;
    __syncthreads();
    float var = (sd[0] + sd[1] + sd[2] + sd[3]) * (1.f / 1024.f);
    float rs = rsqrtf(var + 1e-6f);
    f32x4 gg = *(const f32x4*)&g[c];
    f32x4 bb = *(const f32x4*)&be[c];
    f32x4 o = d * rs * gg + bb;
    *(f32x4*)&out[(size_t)b * 1024 + c] = o;
}

extern "C" void kernel_launch(void* const* d_in, const int* in_sizes, int n_in,
                              void* d_out, int out_size, void* d_ws, size_t ws_size,
                              hipStream_t stream)
{
    const float* key   = (const float*)d_in[0];
    const float* value = (const float*)d_in[1];
    const float* dec   = (const float*)d_in[2];
    const float* Wq = (const float*)d_in[3];  const float* bq = (const float*)d_in[4];
    const float* Wk = (const float*)d_in[5];  /* bk cancels in softmax */
    const float* Wv = (const float*)d_in[7];  const float* bv = (const float*)d_in[8];
    const float* Wo = (const float*)d_in[9];  const float* bo = (const float*)d_in[10];
    const float* W1 = (const float*)d_in[11]; const float* b1 = (const float*)d_in[12];
    const float* W2 = (const float*)d_in[13]; const float* b2 = (const float*)d_in[14];
    const float* g2 = (const float*)d_in[15]; const float* be2 = (const float*)d_in[16];
    const float* gf = (const float*)d_in[17]; const float* bef = (const float*)d_in[18];

    float* ws = (float*)d_ws;
    float* scb  = ws;                   // [8][16][4096]        524288
    float* plp  = scb  + 524288;        // [32][8][16][1024]    4194304
    float* P1   = plp  + 4194304;       // [64][8][1024]        524288
    float* P2   = P1   + 524288;        // [64][8][1024]        524288
    float* Pff1 = P2   + 524288;        // [16][8][4096]        524288
    float* Pff2 = Pff1 + 524288;        // [64][8][1024]        524288
    float* xbuf = Pff2 + 524288;        // [8][1024]            8192
    float* minv = xbuf + 8192;          // [128][2]             256
    unsigned short* u16 = (unsigned short*)(minv + 256);   // [8][16][1024] bf16

    dim3 blk(256);

    // prologue chain (mha1 degenerate): v1=dec@Wv(+bv) ; t1=v1@Wo(+bo) ; q2=t1@Wq(+bq)
    mvV_k<16><<<dim3(4,64), blk, 0, stream>>>(dec, Wv, 1024, 1024, P1);
    mvP_k<16,64,0><<<dim3(4,64), blk, 0, stream>>>(P1, bv, Wo, 1024, 1024, P2);
    mvP_k<16,64,0><<<dim3(4,64), blk, 0, stream>>>(P2, bo, Wq, 1024, 1024, P1);

    // u[b,h,:] = Wk[:,head_h] @ q2[b,head_h]   (q2 = P1 partials + bq)
    u_k<<<dim3(128,4), blk, 0, stream>>>(P1, bq, Wk, u16);

    // attention over key/value with fused softmax
    scores_k<<<dim3(8,64), blk, 0, stream>>>(key, u16, scb);
    smred_k<<<dim3(128), blk, 0, stream>>>(scb, minv);
    pool_k<<<dim3(8,32), blk, 0, stream>>>(value, scb, minv, plp);

    // av = m@Wv per-head ; t2 = (av+bv)@Wo ; x = LN(t2+bo+dec)
    mvH_k<16,32><<<dim3(4,64), blk, 0, stream>>>(plp, Wv, P2);
    mvP_k<16,64,0><<<dim3(4,64), blk, 0, stream>>>(P2, bv, Wo, 1024, 1024, P1);
    lnp_k<<<dim3(8), blk, 0, stream>>>(P1, 64, bo, dec, g2, be2, xbuf);

    // ff: relu(x@W1+b1)@W2 + b2 + x, then final LN
    mvV_k<64><<<dim3(16,16), blk, 0, stream>>>(xbuf, W1, 1024, 4096, Pff1);
    mvP_k<64,16,1><<<dim3(4,64), blk, 0, stream>>>(Pff1, b1, W2, 4096, 1024, Pff2);
    lnp_k<<<dim3(8), blk, 0, stream>>>(Pff2, 64, b2, xbuf, gf, bef, (float*)d_out);

    (void)in_sizes; (void)n_in; (void)out_size; (void)ws_size;
}